// Round 8
// baseline (133.471 us; speedup 1.0000x reference)
//
#include <hip/hip_runtime.h>
#include <math.h>

// B=4, S=4096, D=64, fp32 in/out.
// out[q,:] = (sum_{k<=q} p_k v_k) / (sum_all_j p_j),  p = exp(q.k/8)
// No-max softmax (scores ~N(0,1), |s|max ~6 << 88 overflow) -> den is a
// plain sum; numerator causal-masked per element.
//
// 2 dispatches (each extra dispatch beyond the first costs only its own
// work; a fixed ~47us replay overhead exists regardless — measured R3-R7):
//  prep: K fp32->fp16 once; V fp32->fp16 transposed to [B][D][S+64].
//  attn: NO LDS staging for K/V — MFMA B-fragments are 16 contiguous
//  bytes/lane, loaded global->register from the fp16 buffers (L2-resident,
//  XCD-locked batch). Only P round-trips through wave-private LDS.
//  512-thr blocks (8 waves, wave-private K-tiles TK=32, no main-loop
//  barriers), grid 512 -> 2 blocks/CU = 16 waves/CU.
// Precision: Q scaled by (1/8)*log2e, split hi/lo fp16 (2-term QK);
// p = exp2(acc); P rounded fp16, den summed from ROUNDED p; V single fp16.

typedef _Float16 f16;
typedef __attribute__((ext_vector_type(8))) _Float16 f16x8;
typedef __attribute__((ext_vector_type(4))) _Float16 f16x4;
typedef __attribute__((ext_vector_type(16))) float f32x16;

constexpr int S = 4096, D = 64, TK = 32;
constexpr int B_ = 4;
constexpr int NKT = S / TK;        // 128 K-tiles
constexpr int QB = 32;             // q rows per block
constexpr int WPB = 8;             // waves per block
constexpr int TPW = NKT / WPB;     // 16 tiles per wave
constexpr int LDV = 40;            // ps leading dim (32+8 halfs)
constexpr int SP = S + 64;         // Vt padded row stride (halfs)
constexpr float QSC = 0.125f * 1.44269504088896340736f;  // (1/8)*log2(e)
constexpr size_t NSD = (size_t)B_ * S * D;

// ---------------- prep: K cvt fp16; V transpose [B,S,D]->[B,D,SP] fp16 ----
__global__ __launch_bounds__(256) void prep(
    const float* __restrict__ K, const float* __restrict__ V,
    f16* __restrict__ Kf, f16* __restrict__ Vt) {
  const int bx = blockIdx.x, tid = threadIdx.x;
  if (bx < 1024) {                 // K: 1M elems, float4 per thread
    int i = bx * 256 + tid;
    float4 f = reinterpret_cast<const float4*>(K)[i];
    f16x4 o;
    o[0] = (f16)f.x; o[1] = (f16)f.y; o[2] = (f16)f.z; o[3] = (f16)f.w;
    reinterpret_cast<f16x4*>(Kf)[i] = o;
  } else {                         // V: 256 tiles of 64x64
    __shared__ float tile[64][68];
    const int vb = bx - 1024;
    const int b  = vb >> 6;
    const int s0 = (vb & 63) * 64;
    const float* Vb = V + (size_t)b * S * D;
    #pragma unroll
    for (int r = 0; r < 4; ++r) {
      int f = tid + r * 256;
      int row = f >> 4, c4 = (f & 15) * 4;
      *reinterpret_cast<float4*>(&tile[row][c4]) =
          *reinterpret_cast<const float4*>(Vb + (size_t)(s0 + row) * D + c4);
    }
    __syncthreads();
    const int dim = tid >> 2, sc = (tid & 3) * 16;
    f16* dst = Vt + (size_t)b * D * SP + (size_t)dim * SP + s0 + sc;
    #pragma unroll
    for (int g = 0; g < 4; ++g) {
      f16x4 h;
      #pragma unroll
      for (int e = 0; e < 4; ++e) h[e] = (f16)tile[sc + g * 4 + e][dim];
      reinterpret_cast<f16x4*>(dst)[g] = h;
    }
  }
}

// ---------------- main: direct-global MFMA fragments ----------------------
__global__ __launch_bounds__(512, 4)
void attn(const float* __restrict__ Q, const f16* __restrict__ Kf,
          const f16* __restrict__ Vt, float* __restrict__ O) {
  __shared__ union {
    f16 ps[WPB][QB][LDV];                          // 20.5 KB (wave-private P)
    struct { float nb[4][QB][68]; float db[WPB][QB]; } r;  // 35.8 KB epilogue
  } sm;

  // block -> (b, qb): XCD-locked batch; adjacent blocks pair heavy/light
  const int i = blockIdx.x;
  const int b = (i & 7) >> 1;
  const int t = ((i >> 3) << 1) | (i & 1);            // 0..127
  const int qb = (t & 1) ? (127 - (t >> 1)) : (t >> 1);
  const int q0 = qb * QB;

  const int tid = threadIdx.x;
  const int w = tid >> 6, lane = tid & 63;
  const int l31 = lane & 31, h2 = lane >> 5;

  const size_t bSD = (size_t)b * S * D;
  const f16* Kb = Kf + bSD;
  const f16* Vb = Vt + (size_t)b * D * SP;

  // ---- Q fragments: A-layout (m=l31, k = kc*16 + 8*h2 + j), hi/lo ----
  f16x8 qh[4], qlo[4];
  {
    const float* qr = Q + bSD + (size_t)(q0 + l31) * D;
    #pragma unroll
    for (int kc = 0; kc < 4; ++kc) {
      float4 f0 = *reinterpret_cast<const float4*>(qr + kc * 16 + 8 * h2);
      float4 f1 = *reinterpret_cast<const float4*>(qr + kc * 16 + 8 * h2 + 4);
      float f[8] = {f0.x, f0.y, f0.z, f0.w, f1.x, f1.y, f1.z, f1.w};
      #pragma unroll
      for (int j = 0; j < 8; ++j) {
        float v = f[j] * QSC;
        f16 hi = (f16)v;
        qh[kc][j] = hi;
        qlo[kc][j] = (f16)(v - (float)hi);
      }
    }
  }

  // lane-invariant offsets
  const f16* klane = Kb + l31 * D + 8 * h2;      // + kbase*D + kc*16
  const f16* vlane = Vb + l31 * SP + 8 * h2;     // + kbase + kc2*16 (+32*SP)

  f32x16 on0, on1;
  float ls[16];
  #pragma unroll
  for (int r = 0; r < 16; ++r) { on0[r] = 0.f; on1[r] = 0.f; ls[r] = 0.f; }

  for (int j = 0; j < TPW; ++j) {
    const int kt = (j << 3) | w;               // wave-interleaved tiles
    const int kbase = kt * TK;
    const bool pv = (kbase <= q0);
    const bool diag = (kbase == q0);

    // K B-fragments: 4 x global b128 (L1/L2 hit)
    const f16* kp = klane + kbase * D;
    f16x8 bk0 = *reinterpret_cast<const f16x8*>(kp);
    f16x8 bk1 = *reinterpret_cast<const f16x8*>(kp + 16);
    f16x8 bk2 = *reinterpret_cast<const f16x8*>(kp + 32);
    f16x8 bk3 = *reinterpret_cast<const f16x8*>(kp + 48);

    // QK^T (2-term hi/lo over D=64)
    f32x16 acc;
    #pragma unroll
    for (int r = 0; r < 16; ++r) acc[r] = 0.f;
    acc = __builtin_amdgcn_mfma_f32_32x32x16_f16(qlo[0], bk0, acc, 0, 0, 0);
    acc = __builtin_amdgcn_mfma_f32_32x32x16_f16(qh[0],  bk0, acc, 0, 0, 0);
    acc = __builtin_amdgcn_mfma_f32_32x32x16_f16(qlo[1], bk1, acc, 0, 0, 0);
    acc = __builtin_amdgcn_mfma_f32_32x32x16_f16(qh[1],  bk1, acc, 0, 0, 0);
    acc = __builtin_amdgcn_mfma_f32_32x32x16_f16(qlo[2], bk2, acc, 0, 0, 0);
    acc = __builtin_amdgcn_mfma_f32_32x32x16_f16(qh[2],  bk2, acc, 0, 0, 0);
    acc = __builtin_amdgcn_mfma_f32_32x32x16_f16(qlo[3], bk3, acc, 0, 0, 0);
    acc = __builtin_amdgcn_mfma_f32_32x32x16_f16(qh[3],  bk3, acc, 0, 0, 0);

    // V B-fragments: issue early so latency hides under exp/P-write chain
    f16x8 v00, v01, v10, v11;
    if (pv) {
      const f16* vp = vlane + kbase;
      v00 = *reinterpret_cast<const f16x8*>(vp);
      v01 = *reinterpret_cast<const f16x8*>(vp + 16);
      v10 = *reinterpret_cast<const f16x8*>(vp + 32 * SP);
      v11 = *reinterpret_cast<const f16x8*>(vp + 32 * SP + 16);
    }

    // exp2, den (full row, from ROUNDED p), P write
    #pragma unroll
    for (int r = 0; r < 16; ++r) {
      float pp = __builtin_amdgcn_exp2f(acc[r]);
      f16 ph = (f16)pp;
      ls[r] += (float)ph;
      if (pv) {
        const int row = (r & 3) + 8 * (r >> 2) + 4 * h2;  // C-layout row
        sm.ps[w][row][l31] = (!diag || l31 <= row) ? ph : (f16)0.f;
      }
    }

    // PV: on[q][d] += P[q][k] V[k][d]
    if (pv) {
      asm volatile("s_waitcnt lgkmcnt(0)" ::: "memory");  // wave-private ps RAW
      f16x8 ap0 = *reinterpret_cast<const f16x8*>(&sm.ps[w][l31][8 * h2]);
      f16x8 ap1 = *reinterpret_cast<const f16x8*>(&sm.ps[w][l31][16 + 8 * h2]);
      on0 = __builtin_amdgcn_mfma_f32_32x32x16_f16(ap0, v00, on0, 0, 0, 0);
      on0 = __builtin_amdgcn_mfma_f32_32x32x16_f16(ap1, v01, on0, 0, 0, 0);
      on1 = __builtin_amdgcn_mfma_f32_32x32x16_f16(ap0, v10, on1, 0, 0, 0);
      on1 = __builtin_amdgcn_mfma_f32_32x32x16_f16(ap1, v11, on1, 0, 0, 0);
    }
  }

  // ---- epilogue: reduce den across 32 lanes, then combine 8 waves ----
  #pragma unroll
  for (int r = 0; r < 16; ++r) {
    float v = ls[r];
    #pragma unroll
    for (int x = 1; x <= 16; x <<= 1) v += __shfl_xor(v, x);
    ls[r] = v;
  }
  __syncthreads();    // all waves done with ps; switch to reduction overlay
  if (l31 == 0) {
    #pragma unroll
    for (int r = 0; r < 16; ++r)
      sm.r.db[w][(r & 3) + 8 * (r >> 2) + 4 * h2] = ls[r];
  }
  if (w < 4) {
    #pragma unroll
    for (int r = 0; r < 16; ++r) {
      const int row = (r & 3) + 8 * (r >> 2) + 4 * h2;
      sm.r.nb[w][row][l31]      = on0[r];
      sm.r.nb[w][row][32 + l31] = on1[r];
    }
  }
  __syncthreads();
  if (w >= 4) {
    #pragma unroll
    for (int r = 0; r < 16; ++r) {
      const int row = (r & 3) + 8 * (r >> 2) + 4 * h2;
      sm.r.nb[w - 4][row][l31]      += on0[r];
      sm.r.nb[w - 4][row][32 + l31] += on1[r];
    }
  }
  __syncthreads();

  // ---- final: sum 4 partials, divide by den, coalesced float4 store ----
  const int row = tid >> 4, c4 = (tid & 15) * 4;
  float dsum = 0.f;
  #pragma unroll
  for (int ww = 0; ww < WPB; ++ww) dsum += sm.r.db[ww][row];
  const float inv = 1.f / dsum;
  float4 a0 = *reinterpret_cast<const float4*>(&sm.r.nb[0][row][c4]);
  float4 a1 = *reinterpret_cast<const float4*>(&sm.r.nb[1][row][c4]);
  float4 a2 = *reinterpret_cast<const float4*>(&sm.r.nb[2][row][c4]);
  float4 a3 = *reinterpret_cast<const float4*>(&sm.r.nb[3][row][c4]);
  float4 o;
  o.x = (a0.x + a1.x + a2.x + a3.x) * inv;
  o.y = (a0.y + a1.y + a2.y + a3.y) * inv;
  o.z = (a0.z + a1.z + a2.z + a3.z) * inv;
  o.w = (a0.w + a1.w + a2.w + a3.w) * inv;
  *reinterpret_cast<float4*>(O + bSD + (size_t)(q0 + row) * D + c4) = o;
}

extern "C" void kernel_launch(void* const* d_in, const int* in_sizes, int n_in,
                              void* d_out, int out_size, void* d_ws, size_t ws_size,
                              hipStream_t stream) {
  const float* q = (const float*)d_in[0];
  const float* k = (const float*)d_in[1];
  const float* v = (const float*)d_in[2];
  float* o = (float*)d_out;

  f16* Kf = (f16*)d_ws;                         // NSD halfs (2 MB)
  f16* Vt = Kf + NSD;                           // B_*D*SP halfs (2.1 MB)

  prep<<<dim3(1024 + B_ * (S / 64)), dim3(256), 0, stream>>>(k, v, Kf, Vt);
  attn<<<dim3(512), dim3(512), 0, stream>>>(q, Kf, Vt, o);
}

// Round 9
// 111.347 us; speedup vs baseline: 1.1987x; 1.1987x over previous
//
#include <hip/hip_runtime.h>
#include <math.h>

// B=4, S=4096, D=64, fp32 in/out.
// out[q,:] = (sum_{k<=q} p_k v_k) / (sum_all_j p_j),  p = exp(q.k/8)
// No-max softmax (scores ~N(0,1), |s|max ~6 << 88 overflow) -> den is a
// plain sum; numerator causal-masked per element.
//
// R8 lesson: direct global fragment loads were 128B/8KB-strided GATHERS
// (~32 transactions per b128 instead of 8) -> memory-pipe bound at 75us.
// Fix: prep pre-swizzles K,V into FRAGMENT-MAJOR layout so every main-loop
// fragment load is lane*16B coalesced (1KB/wave, 8 transactions).
//   Kfrag[b][kt][kc][lane][8]:      QK B-operand (lane: n=key l31, h2 picks
//                                   dim-octet; elems = dims kc*16+8h2+j)
//   Vfrag[b][kt][dn*2+kc2][lane][8]: PV B-operand (lane: n=dim dn*32+l31;
//                                   elems = keys kc2*16+8h2+j)
// Main loop: zero barriers (wave-private K-tiles TK=32), P round-trips
// through wave-private LDS. 512-thr blocks, grid 512 -> 16 waves/CU.
// Precision: Q scaled by (1/8)*log2e, split hi/lo fp16 (2-term QK);
// p = exp2(acc); P rounded fp16, den summed from ROUNDED p; V single fp16.

typedef _Float16 f16;
typedef __attribute__((ext_vector_type(8))) _Float16 f16x8;
typedef __attribute__((ext_vector_type(16))) float f32x16;

constexpr int S = 4096, D = 64, TK = 32;
constexpr int B_ = 4;
constexpr int NKT = S / TK;        // 128 K-tiles
constexpr int QB = 32;             // q rows per block
constexpr int WPB = 8;             // waves per block
constexpr int TPW = NKT / WPB;     // 16 tiles per wave
constexpr int LDV = 40;            // ps leading dim (32+8 halfs)
constexpr float QSC = 0.125f * 1.44269504088896340736f;  // (1/8)*log2(e)

// ---------------- prep: swizzle K,V into fragment-major fp16 --------------
__global__ __launch_bounds__(256) void prep(
    const float* __restrict__ K, const float* __restrict__ V,
    f16* __restrict__ Kfrag, f16* __restrict__ Vfrag) {
  const int bx = blockIdx.x, tid = threadIdx.x;
  if (bx < B_ * NKT) {
    // K tile bx = b*128+kt: thread (key, j): dims j*8..j*8+7 of row key
    const float* src = K + (size_t)bx * TK * D;     // tiles are contiguous
    const int key = tid >> 3, j = tid & 7;
    float4 f0 = *reinterpret_cast<const float4*>(src + key * D + j * 8);
    float4 f1 = *reinterpret_cast<const float4*>(src + key * D + j * 8 + 4);
    f16x8 h;
    h[0] = (f16)f0.x; h[1] = (f16)f0.y; h[2] = (f16)f0.z; h[3] = (f16)f0.w;
    h[4] = (f16)f1.x; h[5] = (f16)f1.y; h[6] = (f16)f1.z; h[7] = (f16)f1.w;
    const int kc = j >> 1, h2 = j & 1;
    const int lane = key + 32 * h2;
    *reinterpret_cast<f16x8*>(Kfrag + ((size_t)bx * 4 + kc) * 512 + lane * 8) = h;
  } else {
    // V tile: stage 32x64 fp32 to LDS, emit transposed fragments
    __shared__ float t32[TK][D + 4];
    const int vb = bx - B_ * NKT;
    const float* src = V + (size_t)vb * TK * D;
    #pragma unroll
    for (int r = 0; r < 2; ++r) {
      int f4 = tid + r * 256;            // 512 float4
      int row = f4 >> 4, c4 = (f4 & 15) * 4;
      *reinterpret_cast<float4*>(&t32[row][c4]) =
          *reinterpret_cast<const float4*>(src + row * D + c4);
    }
    __syncthreads();
    const int dn = tid >> 7, kc2 = (tid >> 6) & 1, lane = tid & 63;
    const int l31 = lane & 31, h2 = lane >> 5;
    const int dim = dn * 32 + l31;
    const int k0 = kc2 * 16 + 8 * h2;
    f16x8 h;
    #pragma unroll
    for (int jj = 0; jj < 8; ++jj) h[jj] = (f16)t32[k0 + jj][dim];
    *reinterpret_cast<f16x8*>(
        Vfrag + ((size_t)vb * 4 + dn * 2 + kc2) * 512 + lane * 8) = h;
  }
}

// ---------------- main: coalesced direct-global MFMA fragments ------------
__global__ __launch_bounds__(512, 4)
void attn(const float* __restrict__ Q, const f16* __restrict__ Kfrag,
          const f16* __restrict__ Vfrag, float* __restrict__ O) {
  __shared__ union {
    f16 ps[WPB][QB][LDV];                                  // wave-private P
    struct { float nb[4][QB][68]; float db[WPB][QB]; } r;  // epilogue overlay
  } sm;

  // block -> (b, qb): XCD-locked batch; adjacent blocks pair heavy/light
  const int i = blockIdx.x;
  const int b = (i & 7) >> 1;
  const int t = ((i >> 3) << 1) | (i & 1);            // 0..127
  const int qb = (t & 1) ? (127 - (t >> 1)) : (t >> 1);
  const int q0 = qb * QB;

  const int tid = threadIdx.x;
  const int w = tid >> 6, lane = tid & 63;
  const int l31 = lane & 31, h2 = lane >> 5;

  const size_t bSD = (size_t)b * S * D;

  // ---- Q fragments: A-layout (m=l31, k = kc*16 + 8*h2 + j), hi/lo ----
  f16x8 qh[4], qlo[4];
  {
    const float* qr = Q + bSD + (size_t)(q0 + l31) * D;
    #pragma unroll
    for (int kc = 0; kc < 4; ++kc) {
      float4 f0 = *reinterpret_cast<const float4*>(qr + kc * 16 + 8 * h2);
      float4 f1 = *reinterpret_cast<const float4*>(qr + kc * 16 + 8 * h2 + 4);
      float f[8] = {f0.x, f0.y, f0.z, f0.w, f1.x, f1.y, f1.z, f1.w};
      #pragma unroll
      for (int j = 0; j < 8; ++j) {
        float v = f[j] * QSC;
        f16 hi = (f16)v;
        qh[kc][j] = hi;
        qlo[kc][j] = (f16)(v - (float)hi);
      }
    }
  }

  // fragment-major bases: every load below is base + lane*16B (coalesced)
  const f16* kf = Kfrag + (size_t)b * NKT * 2048 + lane * 8;
  const f16* vf = Vfrag + (size_t)b * NKT * 2048 + lane * 8;

  f32x16 on0, on1;
  float ls[16];
  #pragma unroll
  for (int r = 0; r < 16; ++r) { on0[r] = 0.f; on1[r] = 0.f; ls[r] = 0.f; }

  for (int j = 0; j < TPW; ++j) {
    const int kt = (j << 3) | w;               // wave-interleaved tiles
    const int kbase = kt * TK;
    const bool pv = (kbase <= q0);
    const bool diag = (kbase == q0);

    // V fragments first: latency hides under the QK MFMA chain
    f16x8 v00, v01, v10, v11;
    if (pv) {
      const f16* vp = vf + (size_t)kt * 2048;
      v00 = *reinterpret_cast<const f16x8*>(vp);
      v01 = *reinterpret_cast<const f16x8*>(vp + 512);
      v10 = *reinterpret_cast<const f16x8*>(vp + 1024);
      v11 = *reinterpret_cast<const f16x8*>(vp + 1536);
    }

    // K fragments (4 x coalesced b128)
    const f16* kp = kf + (size_t)kt * 2048;
    f16x8 bk0 = *reinterpret_cast<const f16x8*>(kp);
    f16x8 bk1 = *reinterpret_cast<const f16x8*>(kp + 512);
    f16x8 bk2 = *reinterpret_cast<const f16x8*>(kp + 1024);
    f16x8 bk3 = *reinterpret_cast<const f16x8*>(kp + 1536);

    // QK^T (2-term hi/lo over D=64)
    f32x16 acc;
    #pragma unroll
    for (int r = 0; r < 16; ++r) acc[r] = 0.f;
    acc = __builtin_amdgcn_mfma_f32_32x32x16_f16(qlo[0], bk0, acc, 0, 0, 0);
    acc = __builtin_amdgcn_mfma_f32_32x32x16_f16(qh[0],  bk0, acc, 0, 0, 0);
    acc = __builtin_amdgcn_mfma_f32_32x32x16_f16(qlo[1], bk1, acc, 0, 0, 0);
    acc = __builtin_amdgcn_mfma_f32_32x32x16_f16(qh[1],  bk1, acc, 0, 0, 0);
    acc = __builtin_amdgcn_mfma_f32_32x32x16_f16(qlo[2], bk2, acc, 0, 0, 0);
    acc = __builtin_amdgcn_mfma_f32_32x32x16_f16(qh[2],  bk2, acc, 0, 0, 0);
    acc = __builtin_amdgcn_mfma_f32_32x32x16_f16(qlo[3], bk3, acc, 0, 0, 0);
    acc = __builtin_amdgcn_mfma_f32_32x32x16_f16(qh[3],  bk3, acc, 0, 0, 0);

    // exp2, den (full row, from ROUNDED p), P write
    #pragma unroll
    for (int r = 0; r < 16; ++r) {
      float pp = __builtin_amdgcn_exp2f(acc[r]);
      f16 ph = (f16)pp;
      ls[r] += (float)ph;
      if (pv) {
        const int row = (r & 3) + 8 * (r >> 2) + 4 * h2;  // C-layout row
        sm.ps[w][row][l31] = (!diag || l31 <= row) ? ph : (f16)0.f;
      }
    }

    // PV: on[q][d] += P[q][k] V[k][d]
    if (pv) {
      asm volatile("s_waitcnt lgkmcnt(0)" ::: "memory");  // wave-private ps RAW
      f16x8 ap0 = *reinterpret_cast<const f16x8*>(&sm.ps[w][l31][8 * h2]);
      f16x8 ap1 = *reinterpret_cast<const f16x8*>(&sm.ps[w][l31][16 + 8 * h2]);
      on0 = __builtin_amdgcn_mfma_f32_32x32x16_f16(ap0, v00, on0, 0, 0, 0);
      on0 = __builtin_amdgcn_mfma_f32_32x32x16_f16(ap1, v01, on0, 0, 0, 0);
      on1 = __builtin_amdgcn_mfma_f32_32x32x16_f16(ap0, v10, on1, 0, 0, 0);
      on1 = __builtin_amdgcn_mfma_f32_32x32x16_f16(ap1, v11, on1, 0, 0, 0);
    }
  }

  // ---- epilogue: reduce den across 32 lanes, then combine 8 waves ----
  #pragma unroll
  for (int r = 0; r < 16; ++r) {
    float v = ls[r];
    #pragma unroll
    for (int x = 1; x <= 16; x <<= 1) v += __shfl_xor(v, x);
    ls[r] = v;
  }
  __syncthreads();    // all waves done with ps; switch to reduction overlay
  if (l31 == 0) {
    #pragma unroll
    for (int r = 0; r < 16; ++r)
      sm.r.db[w][(r & 3) + 8 * (r >> 2) + 4 * h2] = ls[r];
  }
  if (w < 4) {
    #pragma unroll
    for (int r = 0; r < 16; ++r) {
      const int row = (r & 3) + 8 * (r >> 2) + 4 * h2;
      sm.r.nb[w][row][l31]      = on0[r];
      sm.r.nb[w][row][32 + l31] = on1[r];
    }
  }
  __syncthreads();
  if (w >= 4) {
    #pragma unroll
    for (int r = 0; r < 16; ++r) {
      const int row = (r & 3) + 8 * (r >> 2) + 4 * h2;
      sm.r.nb[w - 4][row][l31]      += on0[r];
      sm.r.nb[w - 4][row][32 + l31] += on1[r];
    }
  }
  __syncthreads();

  // ---- final: sum 4 partials, divide by den, coalesced float4 store ----
  const int row = tid >> 4, c4 = (tid & 15) * 4;
  float dsum = 0.f;
  #pragma unroll
  for (int ww = 0; ww < WPB; ++ww) dsum += sm.r.db[ww][row];
  const float inv = 1.f / dsum;
  float4 a0 = *reinterpret_cast<const float4*>(&sm.r.nb[0][row][c4]);
  float4 a1 = *reinterpret_cast<const float4*>(&sm.r.nb[1][row][c4]);
  float4 a2 = *reinterpret_cast<const float4*>(&sm.r.nb[2][row][c4]);
  float4 a3 = *reinterpret_cast<const float4*>(&sm.r.nb[3][row][c4]);
  float4 o;
  o.x = (a0.x + a1.x + a2.x + a3.x) * inv;
  o.y = (a0.y + a1.y + a2.y + a3.y) * inv;
  o.z = (a0.z + a1.z + a2.z + a3.z) * inv;
  o.w = (a0.w + a1.w + a2.w + a3.w) * inv;
  *reinterpret_cast<float4*>(O + bSD + (size_t)(q0 + row) * D + c4) = o;
}

extern "C" void kernel_launch(void* const* d_in, const int* in_sizes, int n_in,
                              void* d_out, int out_size, void* d_ws, size_t ws_size,
                              hipStream_t stream) {
  const float* q = (const float*)d_in[0];
  const float* k = (const float*)d_in[1];
  const float* v = (const float*)d_in[2];
  float* o = (float*)d_out;

  f16* Kfrag = (f16*)d_ws;                       // B*S*D halfs (2 MB)
  f16* Vfrag = Kfrag + (size_t)B_ * S * D;       // B*S*D halfs (2 MB)

  prep<<<dim3(2 * B_ * NKT), dim3(256), 0, stream>>>(k, v, Kfrag, Vfrag);
  attn<<<dim3(512), dim3(512), 0, stream>>>(q, Kfrag, Vfrag, o);
}

// Round 10
// 109.733 us; speedup vs baseline: 1.2163x; 1.0147x over previous
//
#include <hip/hip_runtime.h>
#include <math.h>

// B=4, S=4096, D=64, fp32 in/out.
// out[q,:] = (sum_{k<=q} p_k v_k) / (sum_all_j p_j),  p = exp(q.k/8)
// No-max softmax (scores ~N(0,1), |s|max ~6 << 88 overflow) -> den is a
// plain sum; numerator causal-masked per element.
//
// R9 lesson: coalesced fragment loads fixed transactions, but 400 MB of
// fragment re-reads vs a 4 MB/XCD working set -> L2-capacity/latency bound.
// R10: 64 queries per block via PAIRED q-groups (g, 127-g) in 1024-thr
// blocks (16 waves), grid 256 = 1 block/CU all-resident:
//   - waves 2k,2k+1 read the SAME kt sequence for different q-groups ->
//     each L2 line serves 2 waves (L1 reuse); total traffic halves to 200MB
//   - pv(g)+pv(127-g) ~ const -> uniform block work, no straggler
// Per-wave structure/numerics/registers identical to R9 (fits 4 waves/SIMD;
// launch_bounds(1024,4) caps unified regs at 128).
// Precision: Q scaled by (1/8)*log2e, split hi/lo fp16 (2-term QK);
// p = exp2(acc); P rounded fp16, den summed from ROUNDED p; V single fp16.

typedef _Float16 f16;
typedef __attribute__((ext_vector_type(8))) _Float16 f16x8;
typedef __attribute__((ext_vector_type(16))) float f32x16;

constexpr int S = 4096, D = 64, TK = 32;
constexpr int B_ = 4;
constexpr int NKT = S / TK;        // 128 K-tiles
constexpr int WPB = 16;            // waves per block
constexpr int TPW = 16;            // tiles per wave (128 / 8 kidx-slots)
constexpr int LDV = 40;            // ps leading dim (32+8 halfs, 16B-aligned rows)
constexpr float QSC = 0.125f * 1.44269504088896340736f;  // (1/8)*log2(e)

// ---------------- prep: swizzle K,V into fragment-major fp16 --------------
__global__ __launch_bounds__(256) void prep(
    const float* __restrict__ K, const float* __restrict__ V,
    f16* __restrict__ Kfrag, f16* __restrict__ Vfrag) {
  const int bx = blockIdx.x, tid = threadIdx.x;
  if (bx < B_ * NKT) {
    // K tile bx = b*128+kt: thread (key, j): dims j*8..j*8+7 of row key
    const float* src = K + (size_t)bx * TK * D;     // tiles are contiguous
    const int key = tid >> 3, j = tid & 7;
    float4 f0 = *reinterpret_cast<const float4*>(src + key * D + j * 8);
    float4 f1 = *reinterpret_cast<const float4*>(src + key * D + j * 8 + 4);
    f16x8 h;
    h[0] = (f16)f0.x; h[1] = (f16)f0.y; h[2] = (f16)f0.z; h[3] = (f16)f0.w;
    h[4] = (f16)f1.x; h[5] = (f16)f1.y; h[6] = (f16)f1.z; h[7] = (f16)f1.w;
    const int kc = j >> 1, h2 = j & 1;
    const int lane = key + 32 * h2;
    *reinterpret_cast<f16x8*>(Kfrag + ((size_t)bx * 4 + kc) * 512 + lane * 8) = h;
  } else {
    // V tile: stage 32x64 fp32 to LDS, emit transposed fragments
    __shared__ float t32[TK][D + 4];
    const int vb = bx - B_ * NKT;
    const float* src = V + (size_t)vb * TK * D;
    #pragma unroll
    for (int r = 0; r < 2; ++r) {
      int f4 = tid + r * 256;            // 512 float4
      int row = f4 >> 4, c4 = (f4 & 15) * 4;
      *reinterpret_cast<float4*>(&t32[row][c4]) =
          *reinterpret_cast<const float4*>(src + row * D + c4);
    }
    __syncthreads();
    const int dn = tid >> 7, kc2 = (tid >> 6) & 1, lane = tid & 63;
    const int l31 = lane & 31, h2 = lane >> 5;
    const int dim = dn * 32 + l31;
    const int k0 = kc2 * 16 + 8 * h2;
    f16x8 h;
    #pragma unroll
    for (int jj = 0; jj < 8; ++jj) h[jj] = (f16)t32[k0 + jj][dim];
    *reinterpret_cast<f16x8*>(
        Vfrag + ((size_t)vb * 4 + dn * 2 + kc2) * 512 + lane * 8) = h;
  }
}

// ---------------- main: paired q-groups, shared K-tile streams ------------
__global__ __launch_bounds__(1024, 4)
void attn(const float* __restrict__ Q, const f16* __restrict__ Kfrag,
          const f16* __restrict__ Vfrag, float* __restrict__ O) {
  __shared__ union {
    f16 ps[WPB][32][LDV];                                    // 40 KB, wave-private P
    struct { float nb[4][32][68]; float db[2][8][32]; } r;   // 36.9 KB epilogue
  } sm;

  // block -> (b, t): XCD-locked batch; q-groups g1 = t, g2 = 127 - t
  const int i = blockIdx.x;                 // 0..255
  const int b = (i & 7) >> 1;
  const int t = ((i >> 3) << 1) | (i & 1);  // 0..63

  const int tid = threadIdx.x;
  const int w = tid >> 6, lane = tid & 63;
  const int l31 = lane & 31, h2 = lane >> 5;
  const int qt = w & 1;                     // which q-group this wave serves
  const int kidx = w >> 1;                  // 0..7: K-tile stream (shared by pairs)
  const int g = qt ? (127 - t) : t;
  const int q0 = g * TK;                    // wave's first query row

  const size_t bSD = (size_t)b * S * D;

  // ---- Q fragments: A-layout (m=l31, k = kc*16 + 8*h2 + j), hi/lo ----
  f16x8 qh[4], qlo[4];
  {
    const float* qr = Q + bSD + (size_t)(q0 + l31) * D;
    #pragma unroll
    for (int kc = 0; kc < 4; ++kc) {
      float4 f0 = *reinterpret_cast<const float4*>(qr + kc * 16 + 8 * h2);
      float4 f1 = *reinterpret_cast<const float4*>(qr + kc * 16 + 8 * h2 + 4);
      float f[8] = {f0.x, f0.y, f0.z, f0.w, f1.x, f1.y, f1.z, f1.w};
      #pragma unroll
      for (int j = 0; j < 8; ++j) {
        float v = f[j] * QSC;
        f16 hi = (f16)v;
        qh[kc][j] = hi;
        qlo[kc][j] = (f16)(v - (float)hi);
      }
    }
  }

  // fragment-major bases: every load below is base + lane*16B (coalesced)
  const f16* kf = Kfrag + (size_t)b * NKT * 2048 + lane * 8;
  const f16* vf = Vfrag + (size_t)b * NKT * 2048 + lane * 8;

  f32x16 on0, on1;
  float ls[16];
  #pragma unroll
  for (int r = 0; r < 16; ++r) { on0[r] = 0.f; on1[r] = 0.f; ls[r] = 0.f; }

  for (int j = 0; j < TPW; ++j) {
    const int kt = (j << 3) | kidx;            // pair-shared tile stream
    const int kbase = kt * TK;
    const bool pv = (kbase <= q0);
    const bool diag = (kbase == q0);

    // V fragments first: latency hides under the QK MFMA chain
    f16x8 v00, v01, v10, v11;
    if (pv) {
      const f16* vp = vf + (size_t)kt * 2048;
      v00 = *reinterpret_cast<const f16x8*>(vp);
      v01 = *reinterpret_cast<const f16x8*>(vp + 512);
      v10 = *reinterpret_cast<const f16x8*>(vp + 1024);
      v11 = *reinterpret_cast<const f16x8*>(vp + 1536);
    }

    // K fragments (4 x coalesced b128)
    const f16* kp = kf + (size_t)kt * 2048;
    f16x8 bk0 = *reinterpret_cast<const f16x8*>(kp);
    f16x8 bk1 = *reinterpret_cast<const f16x8*>(kp + 512);
    f16x8 bk2 = *reinterpret_cast<const f16x8*>(kp + 1024);
    f16x8 bk3 = *reinterpret_cast<const f16x8*>(kp + 1536);

    // QK^T (2-term hi/lo over D=64)
    f32x16 acc;
    #pragma unroll
    for (int r = 0; r < 16; ++r) acc[r] = 0.f;
    acc = __builtin_amdgcn_mfma_f32_32x32x16_f16(qlo[0], bk0, acc, 0, 0, 0);
    acc = __builtin_amdgcn_mfma_f32_32x32x16_f16(qh[0],  bk0, acc, 0, 0, 0);
    acc = __builtin_amdgcn_mfma_f32_32x32x16_f16(qlo[1], bk1, acc, 0, 0, 0);
    acc = __builtin_amdgcn_mfma_f32_32x32x16_f16(qh[1],  bk1, acc, 0, 0, 0);
    acc = __builtin_amdgcn_mfma_f32_32x32x16_f16(qlo[2], bk2, acc, 0, 0, 0);
    acc = __builtin_amdgcn_mfma_f32_32x32x16_f16(qh[2],  bk2, acc, 0, 0, 0);
    acc = __builtin_amdgcn_mfma_f32_32x32x16_f16(qlo[3], bk3, acc, 0, 0, 0);
    acc = __builtin_amdgcn_mfma_f32_32x32x16_f16(qh[3],  bk3, acc, 0, 0, 0);

    // exp2, den (full row, from ROUNDED p), P write
    #pragma unroll
    for (int r = 0; r < 16; ++r) {
      float pp = __builtin_amdgcn_exp2f(acc[r]);
      f16 ph = (f16)pp;
      ls[r] += (float)ph;
      if (pv) {
        const int row = (r & 3) + 8 * (r >> 2) + 4 * h2;  // C-layout row
        sm.ps[w][row][l31] = (!diag || l31 <= row) ? ph : (f16)0.f;
      }
    }

    // PV: on[q][d] += P[q][k] V[k][d]
    if (pv) {
      asm volatile("s_waitcnt lgkmcnt(0)" ::: "memory");  // wave-private ps RAW
      f16x8 ap0 = *reinterpret_cast<const f16x8*>(&sm.ps[w][l31][8 * h2]);
      f16x8 ap1 = *reinterpret_cast<const f16x8*>(&sm.ps[w][l31][16 + 8 * h2]);
      on0 = __builtin_amdgcn_mfma_f32_32x32x16_f16(ap0, v00, on0, 0, 0, 0);
      on0 = __builtin_amdgcn_mfma_f32_32x32x16_f16(ap1, v01, on0, 0, 0, 0);
      on1 = __builtin_amdgcn_mfma_f32_32x32x16_f16(ap0, v10, on1, 0, 0, 0);
      on1 = __builtin_amdgcn_mfma_f32_32x32x16_f16(ap1, v11, on1, 0, 0, 0);
    }
  }

  // ---- epilogue: den lane-reduce, then two-pass cross-wave combine ----
  #pragma unroll
  for (int r = 0; r < 16; ++r) {
    float v = ls[r];
    #pragma unroll
    for (int x = 1; x <= 16; x <<= 1) v += __shfl_xor(v, x);
    ls[r] = v;
  }
  __syncthreads();                  // ps dead; switch to reduction overlay
  if (l31 == 0) {
    #pragma unroll
    for (int r = 0; r < 16; ++r)
      sm.r.db[qt][w >> 1][(r & 3) + 8 * (r >> 2) + 4 * h2] = ls[r];
  }

  #pragma unroll
  for (int pass = 0; pass < 2; ++pass) {
    const int slot = (w >> 1) & 3;
    if (qt == pass && w < 8) {      // 4 writer waves
      #pragma unroll
      for (int r = 0; r < 16; ++r) {
        const int row = (r & 3) + 8 * (r >> 2) + 4 * h2;
        sm.r.nb[slot][row][l31]      = on0[r];
        sm.r.nb[slot][row][32 + l31] = on1[r];
      }
    }
    __syncthreads();
    if (qt == pass && w >= 8) {     // 4 adder waves
      #pragma unroll
      for (int r = 0; r < 16; ++r) {
        const int row = (r & 3) + 8 * (r >> 2) + 4 * h2;
        sm.r.nb[slot][row][l31]      += on0[r];
        sm.r.nb[slot][row][32 + l31] += on1[r];
      }
    }
    __syncthreads();
    if (tid < 512) {                // final: sum 4 slots, divide, store
      const int row = tid >> 4, c4 = (tid & 15) * 4;
      float dsum = 0.f;
      #pragma unroll
      for (int s = 0; s < 8; ++s) dsum += sm.r.db[pass][s][row];
      const float inv = 1.f / dsum;
      float4 a0 = *reinterpret_cast<const float4*>(&sm.r.nb[0][row][c4]);
      float4 a1 = *reinterpret_cast<const float4*>(&sm.r.nb[1][row][c4]);
      float4 a2 = *reinterpret_cast<const float4*>(&sm.r.nb[2][row][c4]);
      float4 a3 = *reinterpret_cast<const float4*>(&sm.r.nb[3][row][c4]);
      float4 o;
      o.x = (a0.x + a1.x + a2.x + a3.x) * inv;
      o.y = (a0.y + a1.y + a2.y + a3.y) * inv;
      o.z = (a0.z + a1.z + a2.z + a3.z) * inv;
      o.w = (a0.w + a1.w + a2.w + a3.w) * inv;
      const int gp = pass ? (127 - t) : t;
      *reinterpret_cast<float4*>(O + bSD + (size_t)(gp * TK + row) * D + c4) = o;
    }
    __syncthreads();               // nb reads done before next pass overwrites
  }
}

extern "C" void kernel_launch(void* const* d_in, const int* in_sizes, int n_in,
                              void* d_out, int out_size, void* d_ws, size_t ws_size,
                              hipStream_t stream) {
  const float* q = (const float*)d_in[0];
  const float* k = (const float*)d_in[1];
  const float* v = (const float*)d_in[2];
  float* o = (float*)d_out;

  f16* Kfrag = (f16*)d_ws;                       // B*S*D halfs (2 MB)
  f16* Vfrag = Kfrag + (size_t)B_ * S * D;       // B*S*D halfs (2 MB)

  prep<<<dim3(2 * B_ * NKT), dim3(256), 0, stream>>>(k, v, Kfrag, Vfrag);
  attn<<<dim3(256), dim3(1024), 0, stream>>>(q, Kfrag, Vfrag, o);
}